// Round 2
// baseline (913.501 us; speedup 1.0000x reference)
//
#include <hip/hip_runtime.h>
#include <hip/hip_fp16.h>
#include <hip/hip_cooperative_groups.h>

namespace cg = cooperative_groups;

// EquivSetGNN forward, MI355X.
// R15: single cooperative mega-kernel. R14 analysis: every kernel <40us, ideal
// work sum ~130us, but 11 dispatches at ~13us boundary cost each (launch gap +
// ramp/drain) = ~130us dead time. Collapse the whole pipeline into ONE
// hipLaunchCooperativeKernel with grid.sync() at the 9 dependence points.
// __launch_bounds__(256,2) guarantees >=2 blocks/CU (VGPR<=256; LDS union
// 36KB -> 4 blocks/CU), so grid=512 is provably co-resident. binB overlaps
// fused_in_dual (independent) in one partitioned phase.

constexpr int NN = 100000;   // nodes
constexpr int NE = 50000;    // hyperedges
constexpr int NZ = 1280000;  // incidences
constexpr int NG = 256;      // graphs
constexpr int NTILE = NN / 16;  // 6250 row-tiles of 16
constexpr int CB = 196;         // coarse buckets
constexpr int CAP = 8192;       // bucket region capacity (words)
constexpr int CHUNK = 4000;
constexpr int NBLK_A = NZ / CHUNK;  // 320

typedef _Float16 h8 __attribute__((ext_vector_type(8)));
typedef float f4 __attribute__((ext_vector_type(4)));

constexpr int OFF_IN  = 0;
constexpr int OFF_1A  = 8192;
constexpr int OFF_1B  = 12288;
constexpr int OFF_W2  = 16384;
constexpr int OFF_W3  = 24576;
constexpr int OFF_C1  = 28672;
constexpr int OFF_C2  = 32768;
constexpr int WBUF_HALVES = 34816;

struct Params {
  const float* X; const int* src; const int* dst; const int* batch;
  const float* W_in; const float* b_in;
  const float* W1a; const float* b1a; const float* W1b; const float* b1b;
  const float* W2; const float* b2; const float* W3; const float* b3;
  const float* Wc1; const float* bc1; const float* Wc2; const float* bc2;
  float* out;
  __half* xA; __half* xB; __half* hz; __half* Xe;
  float* invE; _Float16* wbuf;
  int* off; int* bcnt; int* roff; int* csr; unsigned int* words;
};

union SMem {
  struct { int cnt[CB]; int base[CB]; } a;                                  // binA
  struct { int buf[CAP]; int hist[256]; int sh[256]; int cur[256]; int shb[256]; } b; // binB 36KB
  float myl[4][16 * 68];                                                    // mfma 17.4KB
  float part[8][32];                                                        // readout
};

__device__ __forceinline__ int lbound(const int* a, int n, int v) {
  int lo = 0, hi = n;
  while (lo < hi) { int m = (lo + hi) >> 1; if (a[m] < v) lo = m + 1; else hi = m; }
  return lo;
}

__device__ __forceinline__ f4 zero4() { f4 z; z[0]=0.f; z[1]=0.f; z[2]=0.f; z[3]=0.f; return z; }

__device__ __forceinline__ h8 ld_a32(const float* p) {
  const f4* v = (const f4*)p;
  f4 lo = v[0], hi = v[1];
  h8 r;
  r[0]=(_Float16)lo[0]; r[1]=(_Float16)lo[1]; r[2]=(_Float16)lo[2]; r[3]=(_Float16)lo[3];
  r[4]=(_Float16)hi[0]; r[5]=(_Float16)hi[1]; r[6]=(_Float16)hi[2]; r[7]=(_Float16)hi[3];
  return r;
}

#define MFMA(a, b, c) __builtin_amdgcn_mfma_f32_16x16x32_f16((a), (b), (c), 0, 0, 0)

// segment-mean gather: one 8-lane group per segment, features across lanes.
// invs==nullptr -> divide by count (zgather); else multiply by invs[g] (ve).
__device__ __forceinline__ void dev_segmean(const __half* rows, const int* idx,
    const int* offs, const float* invs, __half* outr, int nseg,
    int tid, int nthr) {
  int c = tid & 7;
  int ng = nthr >> 3;
  for (int g = tid >> 3; g < nseg; g += ng) {
    int lo = offs[g], hi = offs[g + 1];
    float acc[8];
#pragma unroll
    for (int j = 0; j < 8; ++j) acc[j] = 0.0f;
    int i = lo;
    for (; i + 1 < hi; i += 2) {
      int r0 = idx[i], r1 = idx[i + 1];
      h8 v0 = *(const h8*)(rows + (size_t)r0 * 64 + c * 8);
      h8 v1 = *(const h8*)(rows + (size_t)r1 * 64 + c * 8);
#pragma unroll
      for (int j = 0; j < 8; ++j) acc[j] += (float)v0[j] + (float)v1[j];
    }
    if (i < hi) {
      int r = idx[i];
      h8 v = *(const h8*)(rows + (size_t)r * 64 + c * 8);
#pragma unroll
      for (int j = 0; j < 8; ++j) acc[j] += (float)v[j];
    }
    float s = invs ? invs[g] : ((hi > lo) ? 1.0f / (float)(hi - lo) : 0.0f);
    h8 o;
#pragma unroll
    for (int j = 0; j < 8; ++j) o[j] = (_Float16)(acc[j] * s);
    *(h8*)(outr + (size_t)g * 64 + c * 8) = o;
  }
}

__global__ void __launch_bounds__(256, 2) mega_k(Params P) {
  cg::grid_group gg = cg::this_grid();
  __shared__ SMem sm;
  const int tid = blockIdx.x * 256 + threadIdx.x;
  const int nthr = gridDim.x * 256;
  const int l = threadIdx.x & 63, q = l >> 4, m16 = l & 15, wv = threadIdx.x >> 6;
  const int wid = tid >> 6, nw = nthr >> 6;
  float* myl = sm.myl[wv];

  // ================= phase 0: bcnt zero + roff fill + weight prep =================
  for (int i = tid; i < 256; i += nthr) P.bcnt[i] = 0;
  for (int i = tid; i < NZ; i += nthr) {
    int s = P.src[i];
    int prev = (i == 0) ? -1 : P.src[i - 1];
    for (int v = prev + 1; v <= s; ++v) P.roff[v] = i;
    if (i == NZ - 1) {
      for (int v = s + 1; v <= NN; ++v) P.roff[v] = NZ;
    }
  }
  for (int wtk = tid; wtk < 68 * 64; wtk += nthr) {
    int b = wtk >> 6, lw = wtk & 63;
    const float* srcw; int K, J; _Float16* dstw; int tile;
    if      (b < 16) { srcw = P.W_in; K = 128; J = 64; dstw = P.wbuf + OFF_IN; tile = b; }
    else if (b < 24) { srcw = P.W1a;  K = 64;  J = 64; dstw = P.wbuf + OFF_1A; tile = b - 16; }
    else if (b < 32) { srcw = P.W1b;  K = 64;  J = 64; dstw = P.wbuf + OFF_1B; tile = b - 24; }
    else if (b < 48) { srcw = P.W2;   K = 128; J = 64; dstw = P.wbuf + OFF_W2; tile = b - 32; }
    else if (b < 56) { srcw = P.W3;   K = 64;  J = 64; dstw = P.wbuf + OFF_W3; tile = b - 48; }
    else if (b < 64) { srcw = P.Wc1;  K = 64;  J = 64; dstw = P.wbuf + OFF_C1; tile = b - 56; }
    else             { srcw = P.Wc2;  K = 64;  J = 32; dstw = P.wbuf + OFF_C2; tile = b - 64; }
    int KS = K / 32;
    int jt = tile / KS, ks = tile % KS;
    int qw = lw >> 4, mw = lw & 15;
#pragma unroll
    for (int j = 0; j < 8; ++j)
      dstw[((size_t)tile * 64 + lw) * 8 + j] =
          (_Float16)srcw[(size_t)(ks * 32 + qw * 8 + j) * J + jt * 16 + mw];
  }
  gg.sync();

  // ================= phase 1: binA (coarse bin, packed words) =================
  for (int blk = blockIdx.x; blk < NBLK_A; blk += gridDim.x) {
    int t = threadIdx.x;
    int start = blk * CHUNK;
    for (int i = t; i < CB; i += 256) sm.a.cnt[i] = 0;
    __syncthreads();
    for (int i = start + t; i < start + CHUNK; i += 256)
      atomicAdd(&sm.a.cnt[P.dst[i] >> 8], 1);
    __syncthreads();
    for (int i = t; i < CB; i += 256) sm.a.base[i] = atomicAdd(&P.bcnt[i], sm.a.cnt[i]);
    __syncthreads();
    for (int i = t; i < CB; i += 256) sm.a.cnt[i] = 0;
    __syncthreads();
    for (int i = start + t; i < start + CHUNK; i += 256) {
      int d = P.dst[i];
      int b = d >> 8;
      int p = sm.a.base[b] + atomicAdd(&sm.a.cnt[b], 1);
      P.words[(size_t)b * CAP + p] = (unsigned)P.src[i] | ((unsigned)(d & 255) << 24);
    }
    __syncthreads();
  }
  gg.sync();

  // ========== phase 2: binB (blocks<CB)  ||  fused_in_dual (blocks>=CB) ==========
  if (blockIdx.x < CB) {
    int b = blockIdx.x, t = threadIdx.x;
    int e0 = b << 8;
    int ecnt = min(256, NE - e0);
    int cntb = P.bcnt[b];
    sm.b.shb[t] = (t < CB) ? P.bcnt[t] : 0;
    __syncthreads();
    for (int ofs = 1; ofs < 256; ofs <<= 1) {
      int v = (t >= ofs) ? sm.b.shb[t - ofs] : 0;
      __syncthreads();
      sm.b.shb[t] += v;
      __syncthreads();
    }
    int gbase = sm.b.shb[b] - cntb;
    const unsigned int* wp = P.words + (size_t)b * CAP;
    sm.b.hist[t] = 0;
    __syncthreads();
    for (int i = t; i < cntb; i += 256) atomicAdd(&sm.b.hist[wp[i] >> 24], 1);
    __syncthreads();
    int c = sm.b.hist[t];
    sm.b.sh[t] = c;
    __syncthreads();
    for (int ofs = 1; ofs < 256; ofs <<= 1) {
      int v = (t >= ofs) ? sm.b.sh[t - ofs] : 0;
      __syncthreads();
      sm.b.sh[t] += v;
      __syncthreads();
    }
    int excl = sm.b.sh[t] - c;
    if (t < ecnt) {
      P.off[e0 + t] = gbase + excl;
      P.invE[e0 + t] = 1.0f / (float)max(c, 1);
    }
    if (b == CB - 1 && t == 0) P.off[NE] = NZ;
    sm.b.cur[t] = excl;
    __syncthreads();
    for (int i = t; i < cntb; i += 256) {
      unsigned w = wp[i];
      int s = (int)(w & 0xFFFFFFu);
      int p = atomicAdd(&sm.b.cur[w >> 24], 1);
      if (p < CAP) sm.b.buf[p] = s;
      else P.csr[gbase + p] = s;  // statistically never
    }
    __syncthreads();
    int lim = min(cntb, CAP);
    for (int i = t; i < lim; i += 256) P.csr[gbase + i] = sm.b.buf[i];
  } else {
    // fused_in_dual: x = relu(X@W_in+b); h = relu(x@W1a+b1a)@W1b + b1b
    int wid2 = ((blockIdx.x - CB) * 256 + (int)threadIdx.x) >> 6;
    int nw2 = ((gridDim.x - CB) * 256) >> 6;
    const h8* wip = (const h8*)(P.wbuf + OFF_IN);
    const h8* wap = (const h8*)(P.wbuf + OFF_1A);
    const h8* wbp = (const h8*)(P.wbuf + OFF_1B);
    h8 wi[16], wa[8], wb[8];
#pragma unroll
    for (int f = 0; f < 16; ++f) wi[f] = wip[f * 64 + l];
#pragma unroll
    for (int f = 0; f < 8; ++f) { wa[f] = wap[f * 64 + l]; wb[f] = wbp[f * 64 + l]; }
    float bi[4], ba[4], bb[4];
#pragma unroll
    for (int jt = 0; jt < 4; ++jt) {
      bi[jt] = P.b_in[jt * 16 + m16]; ba[jt] = P.b1a[jt * 16 + m16]; bb[jt] = P.b1b[jt * 16 + m16];
    }
    __half* x = P.xA; __half* h = P.hz;
    for (int t = wid2; t < NTILE; t += nw2) {
      int rbase = t * 16;
      const float* rp = P.X + (size_t)(rbase + m16) * 128 + q * 8;
      h8 a0 = ld_a32(rp), a1 = ld_a32(rp + 32), a2 = ld_a32(rp + 64), a3 = ld_a32(rp + 96);
      f4 acc[4];
#pragma unroll
      for (int jt = 0; jt < 4; ++jt) {
        acc[jt] = zero4();
        acc[jt] = MFMA(a0, wi[jt * 4 + 0], acc[jt]);
        acc[jt] = MFMA(a1, wi[jt * 4 + 1], acc[jt]);
        acc[jt] = MFMA(a2, wi[jt * 4 + 2], acc[jt]);
        acc[jt] = MFMA(a3, wi[jt * 4 + 3], acc[jt]);
      }
#pragma unroll
      for (int jt = 0; jt < 4; ++jt)
#pragma unroll
        for (int r = 0; r < 4; ++r) {
          float v = fmaxf(acc[jt][r] + bi[jt], 0.0f);
          x[(size_t)(rbase + q * 4 + r) * 64 + jt * 16 + m16] = __float2half(v);
          myl[(q * 4 + r) * 68 + jt * 16 + m16] = v;
        }
      h8 t0, t1;
#pragma unroll
      for (int j = 0; j < 8; ++j) t0[j] = (_Float16)myl[m16 * 68 + q * 8 + j];
#pragma unroll
      for (int j = 0; j < 8; ++j) t1[j] = (_Float16)myl[m16 * 68 + 32 + q * 8 + j];
#pragma unroll
      for (int jt = 0; jt < 4; ++jt) {
        acc[jt] = zero4();
        acc[jt] = MFMA(t0, wa[jt * 2 + 0], acc[jt]);
        acc[jt] = MFMA(t1, wa[jt * 2 + 1], acc[jt]);
      }
#pragma unroll
      for (int jt = 0; jt < 4; ++jt)
#pragma unroll
        for (int r = 0; r < 4; ++r)
          myl[(q * 4 + r) * 68 + jt * 16 + m16] = fmaxf(acc[jt][r] + ba[jt], 0.0f);
#pragma unroll
      for (int j = 0; j < 8; ++j) t0[j] = (_Float16)myl[m16 * 68 + q * 8 + j];
#pragma unroll
      for (int j = 0; j < 8; ++j) t1[j] = (_Float16)myl[m16 * 68 + 32 + q * 8 + j];
#pragma unroll
      for (int jt = 0; jt < 4; ++jt) {
        acc[jt] = zero4();
        acc[jt] = MFMA(t0, wb[jt * 2 + 0], acc[jt]);
        acc[jt] = MFMA(t1, wb[jt * 2 + 1], acc[jt]);
      }
#pragma unroll
      for (int jt = 0; jt < 4; ++jt)
#pragma unroll
        for (int r = 0; r < 4; ++r)
          h[(size_t)(rbase + q * 4 + r) * 64 + jt * 16 + m16] = __float2half(acc[jt][r] + bb[jt]);
    }
  }
  gg.sync();

  // ================= layer 1 gathers =================
  dev_segmean(P.hz, P.csr, P.off, P.invE, P.Xe, NE, tid, nthr);   // V->E
  gg.sync();
  dev_segmean(P.Xe, P.dst, P.roff, nullptr, P.hz, NN, tid, nthr); // E->V
  gg.sync();

  // ========== phase 5: layer-1 cat+W3 + layer-2 W1 MLP (z/h alias, tile-local) ==========
  {
    const h8* w2p = (const h8*)(P.wbuf + OFF_W2);
    const h8* w3p = (const h8*)(P.wbuf + OFF_W3);
    const h8* wap = (const h8*)(P.wbuf + OFF_1A);
    const h8* wbp = (const h8*)(P.wbuf + OFF_1B);
    h8 w2[16], w3[8], wa[8], wb[8];
#pragma unroll
    for (int f = 0; f < 16; ++f) w2[f] = w2p[f * 64 + l];
#pragma unroll
    for (int f = 0; f < 8; ++f) { w3[f] = w3p[f * 64 + l]; wa[f] = wap[f * 64 + l]; wb[f] = wbp[f * 64 + l]; }
    float bv2[4], bv3[4], ba[4], bb[4];
#pragma unroll
    for (int jt = 0; jt < 4; ++jt) {
      bv2[jt] = P.b2[jt * 16 + m16]; bv3[jt] = P.b3[jt * 16 + m16];
      ba[jt] = P.b1a[jt * 16 + m16]; bb[jt] = P.b1b[jt * 16 + m16];
    }
    const __half* xin = P.xA; const __half* x0 = P.xA;
    __half* z = P.hz; __half* hh = P.hz; __half* xout = P.xB;
    for (int t = wid; t < NTILE; t += nw) {
      int rbase = t * 16;
      const __half* rp = xin + (size_t)(rbase + m16) * 64 + q * 8;
      h8 a0 = *(const h8*)rp, a1 = *(const h8*)(rp + 32);
      const __half* zr = z + (size_t)(rbase + m16) * 64;
      h8 az0 = *(const h8*)(zr + q * 8), az1 = *(const h8*)(zr + 32 + q * 8);
      f4 acc[4];
#pragma unroll
      for (int jt = 0; jt < 4; ++jt) {
        acc[jt] = zero4();
        acc[jt] = MFMA(a0,  w2[jt * 4 + 0], acc[jt]);
        acc[jt] = MFMA(a1,  w2[jt * 4 + 1], acc[jt]);
        acc[jt] = MFMA(az0, w2[jt * 4 + 2], acc[jt]);
        acc[jt] = MFMA(az1, w2[jt * 4 + 3], acc[jt]);
      }
#pragma unroll
      for (int r = 0; r < 4; ++r) {
        int row = rbase + q * 4 + r;
        float msk = (P.roff[row + 1] > P.roff[row]) ? 0.5f : 0.0f;
#pragma unroll
        for (int jt = 0; jt < 4; ++jt) {
          float val = acc[jt][r] + bv2[jt];
          float x0v = __half2float(x0[(size_t)row * 64 + jt * 16 + m16]);
          myl[(q * 4 + r) * 68 + jt * 16 + m16] = fmaf(msk, val, 0.5f * x0v);
        }
      }
      h8 t0, t1;
#pragma unroll
      for (int j = 0; j < 8; ++j) t0[j] = (_Float16)myl[m16 * 68 + q * 8 + j];
#pragma unroll
      for (int j = 0; j < 8; ++j) t1[j] = (_Float16)myl[m16 * 68 + 32 + q * 8 + j];
#pragma unroll
      for (int jt = 0; jt < 4; ++jt) {
        acc[jt] = zero4();
        acc[jt] = MFMA(t0, w3[jt * 2 + 0], acc[jt]);
        acc[jt] = MFMA(t1, w3[jt * 2 + 1], acc[jt]);
      }
#pragma unroll
      for (int jt = 0; jt < 4; ++jt)
#pragma unroll
        for (int r = 0; r < 4; ++r) {
          float v = fmaxf(acc[jt][r] + bv3[jt], 0.0f);
          xout[(size_t)(rbase + q * 4 + r) * 64 + jt * 16 + m16] = __float2half(v);
          myl[(q * 4 + r) * 68 + jt * 16 + m16] = v;
        }
#pragma unroll
      for (int j = 0; j < 8; ++j) t0[j] = (_Float16)myl[m16 * 68 + q * 8 + j];
#pragma unroll
      for (int j = 0; j < 8; ++j) t1[j] = (_Float16)myl[m16 * 68 + 32 + q * 8 + j];
#pragma unroll
      for (int jt = 0; jt < 4; ++jt) {
        acc[jt] = zero4();
        acc[jt] = MFMA(t0, wa[jt * 2 + 0], acc[jt]);
        acc[jt] = MFMA(t1, wa[jt * 2 + 1], acc[jt]);
      }
#pragma unroll
      for (int jt = 0; jt < 4; ++jt)
#pragma unroll
        for (int r = 0; r < 4; ++r)
          myl[(q * 4 + r) * 68 + jt * 16 + m16] = fmaxf(acc[jt][r] + ba[jt], 0.0f);
#pragma unroll
      for (int j = 0; j < 8; ++j) t0[j] = (_Float16)myl[m16 * 68 + q * 8 + j];
#pragma unroll
      for (int j = 0; j < 8; ++j) t1[j] = (_Float16)myl[m16 * 68 + 32 + q * 8 + j];
#pragma unroll
      for (int jt = 0; jt < 4; ++jt) {
        acc[jt] = zero4();
        acc[jt] = MFMA(t0, wb[jt * 2 + 0], acc[jt]);
        acc[jt] = MFMA(t1, wb[jt * 2 + 1], acc[jt]);
      }
#pragma unroll
      for (int jt = 0; jt < 4; ++jt)
#pragma unroll
        for (int r = 0; r < 4; ++r)
          hh[(size_t)(rbase + q * 4 + r) * 64 + jt * 16 + m16] = __float2half(acc[jt][r] + bb[jt]);
    }
  }
  gg.sync();

  // ================= layer 2 gathers =================
  dev_segmean(P.hz, P.csr, P.off, P.invE, P.Xe, NE, tid, nthr);
  gg.sync();
  dev_segmean(P.Xe, P.dst, P.roff, nullptr, P.hz, NN, tid, nthr);
  gg.sync();

  // ========== phase 8: layer-2 cat+W3 + classifier (logits -> Xe region) ==========
  {
    const h8* w2p = (const h8*)(P.wbuf + OFF_W2);
    const h8* w3p = (const h8*)(P.wbuf + OFF_W3);
    const h8* wc1p = (const h8*)(P.wbuf + OFF_C1);
    const h8* wc2p = (const h8*)(P.wbuf + OFF_C2);
    h8 w2[16], w3[8], wc1[8], wc2[4];
#pragma unroll
    for (int f = 0; f < 16; ++f) w2[f] = w2p[f * 64 + l];
#pragma unroll
    for (int f = 0; f < 8; ++f) { w3[f] = w3p[f * 64 + l]; wc1[f] = wc1p[f * 64 + l]; }
#pragma unroll
    for (int f = 0; f < 4; ++f) wc2[f] = wc2p[f * 64 + l];
    float bv2[4], bv3[4], bv1[4], bvo[2];
#pragma unroll
    for (int jt = 0; jt < 4; ++jt) {
      bv2[jt] = P.b2[jt * 16 + m16]; bv3[jt] = P.b3[jt * 16 + m16]; bv1[jt] = P.bc1[jt * 16 + m16];
    }
#pragma unroll
    for (int jt = 0; jt < 2; ++jt) bvo[jt] = P.bc2[jt * 16 + m16];
    const __half* xin = P.xB; const __half* x0 = P.xA;
    const __half* z = P.hz; __half* outl = P.Xe;
    for (int t = wid; t < NTILE; t += nw) {
      int rbase = t * 16;
      const __half* rp = xin + (size_t)(rbase + m16) * 64 + q * 8;
      h8 a0 = *(const h8*)rp, a1 = *(const h8*)(rp + 32);
      const __half* zr = z + (size_t)(rbase + m16) * 64;
      h8 az0 = *(const h8*)(zr + q * 8), az1 = *(const h8*)(zr + 32 + q * 8);
      f4 acc[4];
#pragma unroll
      for (int jt = 0; jt < 4; ++jt) {
        acc[jt] = zero4();
        acc[jt] = MFMA(a0,  w2[jt * 4 + 0], acc[jt]);
        acc[jt] = MFMA(a1,  w2[jt * 4 + 1], acc[jt]);
        acc[jt] = MFMA(az0, w2[jt * 4 + 2], acc[jt]);
        acc[jt] = MFMA(az1, w2[jt * 4 + 3], acc[jt]);
      }
#pragma unroll
      for (int r = 0; r < 4; ++r) {
        int row = rbase + q * 4 + r;
        float msk = (P.roff[row + 1] > P.roff[row]) ? 0.5f : 0.0f;
#pragma unroll
        for (int jt = 0; jt < 4; ++jt) {
          float val = acc[jt][r] + bv2[jt];
          float x0v = __half2float(x0[(size_t)row * 64 + jt * 16 + m16]);
          myl[(q * 4 + r) * 68 + jt * 16 + m16] = fmaf(msk, val, 0.5f * x0v);
        }
      }
      h8 t0, t1;
#pragma unroll
      for (int j = 0; j < 8; ++j) t0[j] = (_Float16)myl[m16 * 68 + q * 8 + j];
#pragma unroll
      for (int j = 0; j < 8; ++j) t1[j] = (_Float16)myl[m16 * 68 + 32 + q * 8 + j];
#pragma unroll
      for (int jt = 0; jt < 4; ++jt) {
        acc[jt] = zero4();
        acc[jt] = MFMA(t0, w3[jt * 2 + 0], acc[jt]);
        acc[jt] = MFMA(t1, w3[jt * 2 + 1], acc[jt]);
      }
#pragma unroll
      for (int jt = 0; jt < 4; ++jt)
#pragma unroll
        for (int r = 0; r < 4; ++r)
          myl[(q * 4 + r) * 68 + jt * 16 + m16] = fmaxf(acc[jt][r] + bv3[jt], 0.0f);
#pragma unroll
      for (int j = 0; j < 8; ++j) t0[j] = (_Float16)myl[m16 * 68 + q * 8 + j];
#pragma unroll
      for (int j = 0; j < 8; ++j) t1[j] = (_Float16)myl[m16 * 68 + 32 + q * 8 + j];
#pragma unroll
      for (int jt = 0; jt < 4; ++jt) {
        acc[jt] = zero4();
        acc[jt] = MFMA(t0, wc1[jt * 2 + 0], acc[jt]);
        acc[jt] = MFMA(t1, wc1[jt * 2 + 1], acc[jt]);
      }
#pragma unroll
      for (int jt = 0; jt < 4; ++jt)
#pragma unroll
        for (int r = 0; r < 4; ++r)
          myl[(q * 4 + r) * 68 + jt * 16 + m16] = fmaxf(acc[jt][r] + bv1[jt], 0.0f);
#pragma unroll
      for (int j = 0; j < 8; ++j) t0[j] = (_Float16)myl[m16 * 68 + q * 8 + j];
#pragma unroll
      for (int j = 0; j < 8; ++j) t1[j] = (_Float16)myl[m16 * 68 + 32 + q * 8 + j];
      f4 o[2];
#pragma unroll
      for (int jt = 0; jt < 2; ++jt) {
        o[jt] = zero4();
        o[jt] = MFMA(t0, wc2[jt * 2 + 0], o[jt]);
        o[jt] = MFMA(t1, wc2[jt * 2 + 1], o[jt]);
      }
#pragma unroll
      for (int jt = 0; jt < 2; ++jt)
#pragma unroll
        for (int r = 0; r < 4; ++r)
          outl[(size_t)(rbase + q * 4 + r) * 32 + jt * 16 + m16] =
              __float2half(o[jt][r] + bvo[jt]);
    }
  }
  gg.sync();

  // ================= phase 9: per-graph mean readout =================
  for (int g = blockIdx.x; g < NG; g += gridDim.x) {
    int lo = lbound(P.batch, NN, g);
    int hi = lbound(P.batch, NN, g + 1);
    int j = threadIdx.x & 31, r = threadIdx.x >> 5;
    float acc = 0.0f;
    const __half* xc = P.Xe;
    for (int i = lo + r; i < hi; i += 8) acc += __half2float(xc[(size_t)i * 32 + j]);
    sm.part[r][j] = acc;
    __syncthreads();
    if (threadIdx.x < 32) {
      float s = 0.0f;
#pragma unroll
      for (int rr = 0; rr < 8; ++rr) s += sm.part[rr][j];
      P.out[g * 32 + j] = (hi > lo) ? s / (float)(hi - lo) : 0.0f;
    }
    __syncthreads();
  }
}

extern "C" void kernel_launch(void* const* d_in, const int* in_sizes, int n_in,
                              void* d_out, int out_size, void* d_ws, size_t ws_size,
                              hipStream_t stream) {
  Params hp;
  hp.X    = (const float*)d_in[0];
  hp.src  = (const int*)d_in[1];
  hp.dst  = (const int*)d_in[2];
  hp.batch= (const int*)d_in[3];
  hp.W_in = (const float*)d_in[4];
  hp.b_in = (const float*)d_in[5];
  hp.W1a  = (const float*)d_in[6];
  hp.b1a  = (const float*)d_in[7];
  hp.W1b  = (const float*)d_in[8];
  hp.b1b  = (const float*)d_in[9];
  hp.W2   = (const float*)d_in[10];
  hp.b2   = (const float*)d_in[11];
  hp.W3   = (const float*)d_in[12];
  hp.b3   = (const float*)d_in[13];
  hp.Wc1  = (const float*)d_in[14];
  hp.bc1  = (const float*)d_in[15];
  hp.Wc2  = (const float*)d_in[16];
  hp.bc2  = (const float*)d_in[17];
  hp.out  = (float*)d_out;

  // workspace layout (~57 MB), identical to R14
  float* p  = (float*)d_ws;
  hp.xA = (__half*)p; p += (size_t)NN * 32;   // x0 / layer-1 x
  hp.xB = (__half*)p; p += (size_t)NN * 32;   // layer-1 out / layer-2 x
  hp.hz = (__half*)p; p += (size_t)NN * 32;   // h then z (aliased)
  hp.Xe = (__half*)p; p += (size_t)NE * 32;   // Xe; logits at end
  hp.invE = p; p += NE;
  hp.wbuf = (_Float16*)p; p += WBUF_HALVES / 2 + 16;
  int* qq   = (int*)p;
  hp.off  = qq; qq += NE + 1;
  hp.bcnt = qq; qq += 256;
  hp.roff = qq; qq += NN + 1;
  hp.csr  = qq; qq += NZ;                      // 5.12 MB
  hp.words = (unsigned int*)qq; qq += CB * CAP; // 6.4 MB

  // grid: __launch_bounds__(256,2) guarantees >=2 blocks/CU (LDS 36KB -> 4/CU),
  // so 512 blocks are co-resident on 256 CUs. Clamp to 256 if occupancy says 1.
  static int s_grid = 0;
  if (s_grid == 0) {
    int nb = 0;
    hipError_t e = hipOccupancyMaxActiveBlocksPerMultiprocessor(&nb, mega_k, 256, 0);
    s_grid = (e == hipSuccess && nb == 1) ? 256 : 512;
  }
  void* args[] = { (void*)&hp };
  hipLaunchCooperativeKernel((const void*)mega_k, dim3(s_grid), dim3(256), args, 0, stream);
}

// Round 3
// 313.474 us; speedup vs baseline: 2.9141x; 2.9141x over previous
//
#include <hip/hip_runtime.h>
#include <hip/hip_fp16.h>

// EquivSetGNN forward, MI355X.
// R16: revert R15 mega-kernel (913us: single-allocation VGPR=128 spilled the
// fat MFMA phases, 24% occupancy gutted gather MLP, 9 grid.syncs). Back to
// R14's multi-kernel 325us structure with three safe deltas:
//  (1) binB || fused_in_dual block-partition merge (independent deps; the
//      partition ran correctly inside R15) — hides binB, saves a boundary.
//  (2) MFMA grids 512->782: 3128 waves x exactly 2 tiles = no tail (was
//      3.05 tiles/wave => ~24% tail imbalance).
//  (3) gather unroll x2 -> x4: four outstanding 128B row loads per group.

constexpr int NN = 100000;   // nodes
constexpr int NE = 50000;    // hyperedges
constexpr int NZ = 1280000;  // incidences
constexpr int NG = 256;      // graphs
constexpr int NTILE = NN / 16;  // 6250 row-tiles of 16
constexpr int CB = 196;         // coarse buckets
constexpr int CAP = 8192;       // bucket region capacity (words)
constexpr int CHUNK = 4000;
constexpr int NBLK_A = NZ / CHUNK;          // 320
constexpr int NBLK_ROW = (NZ + 255) / 256;  // 5000
constexpr int MMGRID = 782;                 // 3128 waves: 6250 tiles -> 2/wave

typedef _Float16 h8 __attribute__((ext_vector_type(8)));
typedef float f4 __attribute__((ext_vector_type(4)));

constexpr int OFF_IN  = 0;
constexpr int OFF_1A  = 8192;
constexpr int OFF_1B  = 12288;
constexpr int OFF_W2  = 16384;
constexpr int OFF_W3  = 24576;
constexpr int OFF_C1  = 28672;
constexpr int OFF_C2  = 32768;
constexpr int WBUF_HALVES = 34816;

__device__ __forceinline__ int lbound(const int* a, int n, int v) {
  int lo = 0, hi = n;
  while (lo < hi) { int m = (lo + hi) >> 1; if (a[m] < v) lo = m + 1; else hi = m; }
  return lo;
}

__device__ __forceinline__ f4 zero4() { f4 z; z[0]=0.f; z[1]=0.f; z[2]=0.f; z[3]=0.f; return z; }

__device__ __forceinline__ h8 ld_a32(const float* p) {
  const f4* v = (const f4*)p;
  f4 lo = v[0], hi = v[1];
  h8 r;
  r[0]=(_Float16)lo[0]; r[1]=(_Float16)lo[1]; r[2]=(_Float16)lo[2]; r[3]=(_Float16)lo[3];
  r[4]=(_Float16)hi[0]; r[5]=(_Float16)hi[1]; r[6]=(_Float16)hi[2]; r[7]=(_Float16)hi[3];
  return r;
}

#define MFMA(a, b, c) __builtin_amdgcn_mfma_f32_16x16x32_f16((a), (b), (c), 0, 0, 0)

// ---- Pass A: coarse bin into fixed-capacity regions, packed ((dst&255)<<24 | src) ----
__global__ void __launch_bounds__(256) binA_k(const int* __restrict__ src,
    const int* __restrict__ dst, int* __restrict__ bcnt, unsigned int* __restrict__ words) {
  __shared__ int cnt[CB];
  __shared__ int base[CB];
  int t = threadIdx.x;
  int start = blockIdx.x * CHUNK;
  for (int i = t; i < CB; i += 256) cnt[i] = 0;
  __syncthreads();
  for (int i = start + t; i < start + CHUNK; i += 256)
    atomicAdd(&cnt[dst[i] >> 8], 1);
  __syncthreads();
  for (int i = t; i < CB; i += 256) base[i] = atomicAdd(&bcnt[i], cnt[i]);
  __syncthreads();
  for (int i = t; i < CB; i += 256) cnt[i] = 0;  // reuse as cursor
  __syncthreads();
  for (int i = start + t; i < start + CHUNK; i += 256) {
    int d = dst[i];
    int b = d >> 8;
    int p = base[b] + atomicAdd(&cnt[b], 1);
    words[(size_t)b * CAP + p] = (unsigned)src[i] | ((unsigned)(d & 255) << 24);
  }
}

// ---- merged: roff from sorted src (+bcnt zero) | weight-fragment prep ----
__global__ void __launch_bounds__(256) prep_misc_k(const int* __restrict__ src,
    int* __restrict__ roff, int* __restrict__ bcnt, int n, int nnz,
    const float* __restrict__ W_in, const float* __restrict__ W1a,
    const float* __restrict__ W1b, const float* __restrict__ W2,
    const float* __restrict__ W3,  const float* __restrict__ Wc1,
    const float* __restrict__ Wc2, _Float16* __restrict__ wbuf) {
  int blk = blockIdx.x;
  if (blk < NBLK_ROW) {
    if (blk == 0 && threadIdx.x < 256) bcnt[threadIdx.x] = 0;
    int i = blk * 256 + threadIdx.x;
    if (i >= nnz) return;
    int s = src[i];
    int prev = (i == 0) ? -1 : src[i - 1];
    for (int v = prev + 1; v <= s; ++v) roff[v] = i;
    if (i == nnz - 1) {
      for (int v = s + 1; v <= n; ++v) roff[v] = nnz;
    }
    return;
  }
  int b = blk - NBLK_ROW;
  int l = threadIdx.x;
  if (l >= 64) return;
  const float* srcw; int K, J; _Float16* dstw; int tile;
  if      (b < 16) { srcw = W_in; K = 128; J = 64; dstw = wbuf + OFF_IN; tile = b; }
  else if (b < 24) { srcw = W1a;  K = 64;  J = 64; dstw = wbuf + OFF_1A; tile = b - 16; }
  else if (b < 32) { srcw = W1b;  K = 64;  J = 64; dstw = wbuf + OFF_1B; tile = b - 24; }
  else if (b < 48) { srcw = W2;   K = 128; J = 64; dstw = wbuf + OFF_W2; tile = b - 32; }
  else if (b < 56) { srcw = W3;   K = 64;  J = 64; dstw = wbuf + OFF_W3; tile = b - 48; }
  else if (b < 64) { srcw = Wc1;  K = 64;  J = 64; dstw = wbuf + OFF_C1; tile = b - 56; }
  else             { srcw = Wc2;  K = 64;  J = 32; dstw = wbuf + OFF_C2; tile = b - 64; }
  int KS = K / 32;
  int jt = tile / KS, ks = tile % KS;
  int q = l >> 4, m = l & 15;
#pragma unroll
  for (int j = 0; j < 8; ++j)
    dstw[((size_t)tile * 64 + l) * 8 + j] =
        (_Float16)srcw[(size_t)(ks * 32 + q * 8 + j) * J + jt * 16 + m];
}

// ---- merged: binB (blocks<CB) || fused_in_dual (blocks>=CB). Independent deps:
// binB needs binA's words/bcnt; in_dual needs prep's wbuf + X. No sync needed.
union MergedSMem {
  struct { int buf[CAP]; int hist[256]; int sh[256]; int cur[256]; int shb[256]; } b;
  float myl[4][16 * 68];
};

__global__ void __launch_bounds__(256) binB_indual_k(
    const unsigned int* __restrict__ words, const int* __restrict__ bcnt,
    int* __restrict__ off, float* __restrict__ invE, int* __restrict__ csr,
    const float* __restrict__ A, const _Float16* __restrict__ wbuf,
    const float* __restrict__ b_in, const float* __restrict__ b1a,
    const float* __restrict__ b1b, __half* __restrict__ x, __half* __restrict__ h) {
  __shared__ MergedSMem sm;
  if (blockIdx.x < CB) {
    int b = blockIdx.x, t = threadIdx.x;
    int e0 = b << 8;
    int ecnt = min(256, NE - e0);
    int cntb = bcnt[b];
    sm.b.shb[t] = (t < CB) ? bcnt[t] : 0;
    __syncthreads();
    for (int ofs = 1; ofs < 256; ofs <<= 1) {
      int v = (t >= ofs) ? sm.b.shb[t - ofs] : 0;
      __syncthreads();
      sm.b.shb[t] += v;
      __syncthreads();
    }
    int gbase = sm.b.shb[b] - cntb;
    const unsigned int* wp = words + (size_t)b * CAP;
    sm.b.hist[t] = 0;
    __syncthreads();
    for (int i = t; i < cntb; i += 256) atomicAdd(&sm.b.hist[wp[i] >> 24], 1);
    __syncthreads();
    int c = sm.b.hist[t];
    sm.b.sh[t] = c;
    __syncthreads();
    for (int ofs = 1; ofs < 256; ofs <<= 1) {
      int v = (t >= ofs) ? sm.b.sh[t - ofs] : 0;
      __syncthreads();
      sm.b.sh[t] += v;
      __syncthreads();
    }
    int excl = sm.b.sh[t] - c;
    if (t < ecnt) {
      off[e0 + t] = gbase + excl;
      invE[e0 + t] = 1.0f / (float)max(c, 1);
    }
    if (b == CB - 1 && t == 0) off[NE] = NZ;
    sm.b.cur[t] = excl;
    __syncthreads();
    for (int i = t; i < cntb; i += 256) {
      unsigned w = wp[i];
      int s = (int)(w & 0xFFFFFFu);
      int p = atomicAdd(&sm.b.cur[w >> 24], 1);
      if (p < CAP) sm.b.buf[p] = s;
      else csr[gbase + p] = s;  // statistically never
    }
    __syncthreads();
    int lim = min(cntb, CAP);
    for (int i = t; i < lim; i += 256) csr[gbase + i] = sm.b.buf[i];
    return;
  }
  // ---- fused_in_dual branch ----
  int l = threadIdx.x & 63, q = l >> 4, m16 = l & 15, wv = threadIdx.x >> 6;
  int wid = ((blockIdx.x - CB) * 256 + (int)threadIdx.x) >> 6;
  int nw = (MMGRID * 256) >> 6;
  const h8* wip = (const h8*)(wbuf + OFF_IN);
  const h8* wap = (const h8*)(wbuf + OFF_1A);
  const h8* wbp = (const h8*)(wbuf + OFF_1B);
  h8 wi[16], wa[8], wb[8];
#pragma unroll
  for (int f = 0; f < 16; ++f) wi[f] = wip[f * 64 + l];
#pragma unroll
  for (int f = 0; f < 8; ++f) { wa[f] = wap[f * 64 + l]; wb[f] = wbp[f * 64 + l]; }
  float bi[4], ba[4], bb[4];
#pragma unroll
  for (int jt = 0; jt < 4; ++jt) {
    bi[jt] = b_in[jt * 16 + m16]; ba[jt] = b1a[jt * 16 + m16]; bb[jt] = b1b[jt * 16 + m16];
  }
  float* myl = sm.myl[wv];
  for (int t = wid; t < NTILE; t += nw) {
    int rbase = t * 16;
    const float* rp = A + (size_t)(rbase + m16) * 128 + q * 8;
    h8 a0 = ld_a32(rp), a1 = ld_a32(rp + 32), a2 = ld_a32(rp + 64), a3 = ld_a32(rp + 96);
    f4 acc[4];
#pragma unroll
    for (int jt = 0; jt < 4; ++jt) {
      acc[jt] = zero4();
      acc[jt] = MFMA(a0, wi[jt * 4 + 0], acc[jt]);
      acc[jt] = MFMA(a1, wi[jt * 4 + 1], acc[jt]);
      acc[jt] = MFMA(a2, wi[jt * 4 + 2], acc[jt]);
      acc[jt] = MFMA(a3, wi[jt * 4 + 3], acc[jt]);
    }
#pragma unroll
    for (int jt = 0; jt < 4; ++jt)
#pragma unroll
      for (int r = 0; r < 4; ++r) {
        float v = fmaxf(acc[jt][r] + bi[jt], 0.0f);
        x[(size_t)(rbase + q * 4 + r) * 64 + jt * 16 + m16] = __float2half(v);
        myl[(q * 4 + r) * 68 + jt * 16 + m16] = v;
      }
    h8 t0, t1;
#pragma unroll
    for (int j = 0; j < 8; ++j) t0[j] = (_Float16)myl[m16 * 68 + q * 8 + j];
#pragma unroll
    for (int j = 0; j < 8; ++j) t1[j] = (_Float16)myl[m16 * 68 + 32 + q * 8 + j];
#pragma unroll
    for (int jt = 0; jt < 4; ++jt) {
      acc[jt] = zero4();
      acc[jt] = MFMA(t0, wa[jt * 2 + 0], acc[jt]);
      acc[jt] = MFMA(t1, wa[jt * 2 + 1], acc[jt]);
    }
#pragma unroll
    for (int jt = 0; jt < 4; ++jt)
#pragma unroll
      for (int r = 0; r < 4; ++r)
        myl[(q * 4 + r) * 68 + jt * 16 + m16] = fmaxf(acc[jt][r] + ba[jt], 0.0f);
#pragma unroll
    for (int j = 0; j < 8; ++j) t0[j] = (_Float16)myl[m16 * 68 + q * 8 + j];
#pragma unroll
    for (int j = 0; j < 8; ++j) t1[j] = (_Float16)myl[m16 * 68 + 32 + q * 8 + j];
#pragma unroll
    for (int jt = 0; jt < 4; ++jt) {
      acc[jt] = zero4();
      acc[jt] = MFMA(t0, wb[jt * 2 + 0], acc[jt]);
      acc[jt] = MFMA(t1, wb[jt * 2 + 1], acc[jt]);
    }
#pragma unroll
    for (int jt = 0; jt < 4; ++jt)
#pragma unroll
      for (int r = 0; r < 4; ++r)
        h[(size_t)(rbase + q * 4 + r) * 64 + jt * 16 + m16] = __float2half(acc[jt][r] + bb[jt]);
  }
}

// ---- V->E pull: 8-lane group per edge, unroll x4 ----
__global__ void __launch_bounds__(256) ve_pull_k(const __half* __restrict__ h,
    const int* __restrict__ csr, const int* __restrict__ off,
    const float* __restrict__ invE, __half* __restrict__ Xe, int e) {
  int gid = (blockIdx.x * blockDim.x + threadIdx.x) >> 3;
  if (gid >= e) return;
  int c = threadIdx.x & 7;
  int lo = off[gid], end = off[gid + 1];
  float acc[8];
#pragma unroll
  for (int j = 0; j < 8; ++j) acc[j] = 0.0f;
  int i = lo;
  for (; i + 3 < end; i += 4) {
    int r0 = csr[i], r1 = csr[i + 1], r2 = csr[i + 2], r3 = csr[i + 3];
    h8 v0 = *(const h8*)(h + (size_t)r0 * 64 + c * 8);
    h8 v1 = *(const h8*)(h + (size_t)r1 * 64 + c * 8);
    h8 v2 = *(const h8*)(h + (size_t)r2 * 64 + c * 8);
    h8 v3 = *(const h8*)(h + (size_t)r3 * 64 + c * 8);
#pragma unroll
    for (int j = 0; j < 8; ++j)
      acc[j] += ((float)v0[j] + (float)v1[j]) + ((float)v2[j] + (float)v3[j]);
  }
  for (; i < end; ++i) {
    int r = csr[i];
    h8 v = *(const h8*)(h + (size_t)r * 64 + c * 8);
#pragma unroll
    for (int j = 0; j < 8; ++j) acc[j] += (float)v[j];
  }
  float s = invE[gid];
  h8 o;
#pragma unroll
  for (int j = 0; j < 8; ++j) o[j] = (_Float16)(acc[j] * s);
  *(h8*)(Xe + (size_t)gid * 64 + c * 8) = o;
}

// ---- E->V pull: 8-lane group per node, unroll x4 ----
__global__ void __launch_bounds__(256) zgather_k(const __half* __restrict__ Xe,
    const int* __restrict__ dstArr, const int* __restrict__ roff,
    __half* __restrict__ z, int n) {
  int gid = (blockIdx.x * blockDim.x + threadIdx.x) >> 3;
  if (gid >= n) return;
  int c = threadIdx.x & 7;
  int lo = roff[gid], hi = roff[gid + 1];
  float acc[8];
#pragma unroll
  for (int j = 0; j < 8; ++j) acc[j] = 0.0f;
  int i = lo;
  for (; i + 3 < hi; i += 4) {
    int r0 = dstArr[i], r1 = dstArr[i + 1], r2 = dstArr[i + 2], r3 = dstArr[i + 3];
    h8 v0 = *(const h8*)(Xe + (size_t)r0 * 64 + c * 8);
    h8 v1 = *(const h8*)(Xe + (size_t)r1 * 64 + c * 8);
    h8 v2 = *(const h8*)(Xe + (size_t)r2 * 64 + c * 8);
    h8 v3 = *(const h8*)(Xe + (size_t)r3 * 64 + c * 8);
#pragma unroll
    for (int j = 0; j < 8; ++j)
      acc[j] += ((float)v0[j] + (float)v1[j]) + ((float)v2[j] + (float)v3[j]);
  }
  for (; i < hi; ++i) {
    int r = dstArr[i];
    h8 v = *(const h8*)(Xe + (size_t)r * 64 + c * 8);
#pragma unroll
    for (int j = 0; j < 8; ++j) acc[j] += (float)v[j];
  }
  float s = (hi > lo) ? 1.0f / (float)(hi - lo) : 0.0f;
  h8 o;
#pragma unroll
  for (int j = 0; j < 8; ++j) o[j] = (_Float16)(acc[j] * s);
  *(h8*)(z + (size_t)gid * 64 + c * 8) = o;
}

// ---- fused: layer-1 catmm_w3 + layer-2 W1 MLP (z/h alias, tile-local) ----
__global__ void __launch_bounds__(256) fused_cat_dual(const __half* xin,
    const __half* z, const __half* x0,
    const int* __restrict__ roff, const _Float16* __restrict__ wbuf,
    const float* __restrict__ b2, const float* __restrict__ b3,
    const float* __restrict__ b1a, const float* __restrict__ b1b,
    __half* __restrict__ xout, __half* h, int ntiles) {
  __shared__ float lds[4][16 * 68];
  int l = threadIdx.x & 63, q = l >> 4, m16 = l & 15, wv = threadIdx.x >> 6;
  int wid = (blockIdx.x * blockDim.x + threadIdx.x) >> 6;
  int nw = (gridDim.x * blockDim.x) >> 6;
  const h8* w2p = (const h8*)(wbuf + OFF_W2);
  const h8* w3p = (const h8*)(wbuf + OFF_W3);
  const h8* wap = (const h8*)(wbuf + OFF_1A);
  const h8* wbp = (const h8*)(wbuf + OFF_1B);
  h8 w2[16], w3[8], wa[8], wb[8];
#pragma unroll
  for (int f = 0; f < 16; ++f) w2[f] = w2p[f * 64 + l];
#pragma unroll
  for (int f = 0; f < 8; ++f) { w3[f] = w3p[f * 64 + l]; wa[f] = wap[f * 64 + l]; wb[f] = wbp[f * 64 + l]; }
  float bv2[4], bv3[4], ba[4], bb[4];
#pragma unroll
  for (int jt = 0; jt < 4; ++jt) {
    bv2[jt] = b2[jt * 16 + m16]; bv3[jt] = b3[jt * 16 + m16];
    ba[jt] = b1a[jt * 16 + m16]; bb[jt] = b1b[jt * 16 + m16];
  }
  float* myl = lds[wv];
  for (int t = wid; t < ntiles; t += nw) {
    int rbase = t * 16;
    const __half* rp = xin + (size_t)(rbase + m16) * 64 + q * 8;
    h8 a0 = *(const h8*)rp, a1 = *(const h8*)(rp + 32);
    const __half* zr = z + (size_t)(rbase + m16) * 64;
    h8 az0 = *(const h8*)(zr + q * 8), az1 = *(const h8*)(zr + 32 + q * 8);
    f4 acc[4];
#pragma unroll
    for (int jt = 0; jt < 4; ++jt) {
      acc[jt] = zero4();
      acc[jt] = MFMA(a0,  w2[jt * 4 + 0], acc[jt]);
      acc[jt] = MFMA(a1,  w2[jt * 4 + 1], acc[jt]);
      acc[jt] = MFMA(az0, w2[jt * 4 + 2], acc[jt]);
      acc[jt] = MFMA(az1, w2[jt * 4 + 3], acc[jt]);
    }
#pragma unroll
    for (int r = 0; r < 4; ++r) {
      int row = rbase + q * 4 + r;
      float msk = (roff[row + 1] > roff[row]) ? 0.5f : 0.0f;
#pragma unroll
      for (int jt = 0; jt < 4; ++jt) {
        float val = acc[jt][r] + bv2[jt];
        float x0v = __half2float(x0[(size_t)row * 64 + jt * 16 + m16]);
        myl[(q * 4 + r) * 68 + jt * 16 + m16] = fmaf(msk, val, 0.5f * x0v);
      }
    }
    h8 t0, t1;
#pragma unroll
    for (int j = 0; j < 8; ++j) t0[j] = (_Float16)myl[m16 * 68 + q * 8 + j];
#pragma unroll
    for (int j = 0; j < 8; ++j) t1[j] = (_Float16)myl[m16 * 68 + 32 + q * 8 + j];
#pragma unroll
    for (int jt = 0; jt < 4; ++jt) {
      acc[jt] = zero4();
      acc[jt] = MFMA(t0, w3[jt * 2 + 0], acc[jt]);
      acc[jt] = MFMA(t1, w3[jt * 2 + 1], acc[jt]);
    }
#pragma unroll
    for (int jt = 0; jt < 4; ++jt)
#pragma unroll
      for (int r = 0; r < 4; ++r) {
        float v = fmaxf(acc[jt][r] + bv3[jt], 0.0f);
        xout[(size_t)(rbase + q * 4 + r) * 64 + jt * 16 + m16] = __float2half(v);
        myl[(q * 4 + r) * 68 + jt * 16 + m16] = v;
      }
#pragma unroll
    for (int j = 0; j < 8; ++j) t0[j] = (_Float16)myl[m16 * 68 + q * 8 + j];
#pragma unroll
    for (int j = 0; j < 8; ++j) t1[j] = (_Float16)myl[m16 * 68 + 32 + q * 8 + j];
#pragma unroll
    for (int jt = 0; jt < 4; ++jt) {
      acc[jt] = zero4();
      acc[jt] = MFMA(t0, wa[jt * 2 + 0], acc[jt]);
      acc[jt] = MFMA(t1, wa[jt * 2 + 1], acc[jt]);
    }
#pragma unroll
    for (int jt = 0; jt < 4; ++jt)
#pragma unroll
      for (int r = 0; r < 4; ++r)
        myl[(q * 4 + r) * 68 + jt * 16 + m16] = fmaxf(acc[jt][r] + ba[jt], 0.0f);
#pragma unroll
    for (int j = 0; j < 8; ++j) t0[j] = (_Float16)myl[m16 * 68 + q * 8 + j];
#pragma unroll
    for (int j = 0; j < 8; ++j) t1[j] = (_Float16)myl[m16 * 68 + 32 + q * 8 + j];
#pragma unroll
    for (int jt = 0; jt < 4; ++jt) {
      acc[jt] = zero4();
      acc[jt] = MFMA(t0, wb[jt * 2 + 0], acc[jt]);
      acc[jt] = MFMA(t1, wb[jt * 2 + 1], acc[jt]);
    }
#pragma unroll
    for (int jt = 0; jt < 4; ++jt)
#pragma unroll
      for (int r = 0; r < 4; ++r)
        h[(size_t)(rbase + q * 4 + r) * 64 + jt * 16 + m16] = __float2half(acc[jt][r] + bb[jt]);
  }
}

// ---- fused: layer-2 catmm_w3 + classifier ----
__global__ void __launch_bounds__(256) fused_cat_cls(const __half* __restrict__ xin,
    const __half* __restrict__ z, const __half* __restrict__ x0,
    const int* __restrict__ roff, const _Float16* __restrict__ wbuf,
    const float* __restrict__ b2, const float* __restrict__ b3,
    const float* __restrict__ bc1, const float* __restrict__ bc2,
    __half* __restrict__ out, int ntiles) {
  __shared__ float lds[4][16 * 68];
  int l = threadIdx.x & 63, q = l >> 4, m16 = l & 15, wv = threadIdx.x >> 6;
  int wid = (blockIdx.x * blockDim.x + threadIdx.x) >> 6;
  int nw = (gridDim.x * blockDim.x) >> 6;
  const h8* w2p = (const h8*)(wbuf + OFF_W2);
  const h8* w3p = (const h8*)(wbuf + OFF_W3);
  const h8* wc1p = (const h8*)(wbuf + OFF_C1);
  const h8* wc2p = (const h8*)(wbuf + OFF_C2);
  h8 w2[16], w3[8], wc1[8], wc2[4];
#pragma unroll
  for (int f = 0; f < 16; ++f) w2[f] = w2p[f * 64 + l];
#pragma unroll
  for (int f = 0; f < 8; ++f) { w3[f] = w3p[f * 64 + l]; wc1[f] = wc1p[f * 64 + l]; }
#pragma unroll
  for (int f = 0; f < 4; ++f) wc2[f] = wc2p[f * 64 + l];
  float bv2[4], bv3[4], bv1[4], bvo[2];
#pragma unroll
  for (int jt = 0; jt < 4; ++jt) {
    bv2[jt] = b2[jt * 16 + m16]; bv3[jt] = b3[jt * 16 + m16]; bv1[jt] = bc1[jt * 16 + m16];
  }
#pragma unroll
  for (int jt = 0; jt < 2; ++jt) bvo[jt] = bc2[jt * 16 + m16];
  float* myl = lds[wv];
  for (int t = wid; t < ntiles; t += nw) {
    int rbase = t * 16;
    const __half* rp = xin + (size_t)(rbase + m16) * 64 + q * 8;
    h8 a0 = *(const h8*)rp, a1 = *(const h8*)(rp + 32);
    const __half* zr = z + (size_t)(rbase + m16) * 64;
    h8 az0 = *(const h8*)(zr + q * 8), az1 = *(const h8*)(zr + 32 + q * 8);
    f4 acc[4];
#pragma unroll
    for (int jt = 0; jt < 4; ++jt) {
      acc[jt] = zero4();
      acc[jt] = MFMA(a0,  w2[jt * 4 + 0], acc[jt]);
      acc[jt] = MFMA(a1,  w2[jt * 4 + 1], acc[jt]);
      acc[jt] = MFMA(az0, w2[jt * 4 + 2], acc[jt]);
      acc[jt] = MFMA(az1, w2[jt * 4 + 3], acc[jt]);
    }
#pragma unroll
    for (int r = 0; r < 4; ++r) {
      int row = rbase + q * 4 + r;
      float msk = (roff[row + 1] > roff[row]) ? 0.5f : 0.0f;
#pragma unroll
      for (int jt = 0; jt < 4; ++jt) {
        float val = acc[jt][r] + bv2[jt];
        float x0v = __half2float(x0[(size_t)row * 64 + jt * 16 + m16]);
        myl[(q * 4 + r) * 68 + jt * 16 + m16] = fmaf(msk, val, 0.5f * x0v);
      }
    }
    h8 t0, t1;
#pragma unroll
    for (int j = 0; j < 8; ++j) t0[j] = (_Float16)myl[m16 * 68 + q * 8 + j];
#pragma unroll
    for (int j = 0; j < 8; ++j) t1[j] = (_Float16)myl[m16 * 68 + 32 + q * 8 + j];
#pragma unroll
    for (int jt = 0; jt < 4; ++jt) {
      acc[jt] = zero4();
      acc[jt] = MFMA(t0, w3[jt * 2 + 0], acc[jt]);
      acc[jt] = MFMA(t1, w3[jt * 2 + 1], acc[jt]);
    }
#pragma unroll
    for (int jt = 0; jt < 4; ++jt)
#pragma unroll
      for (int r = 0; r < 4; ++r)
        myl[(q * 4 + r) * 68 + jt * 16 + m16] = fmaxf(acc[jt][r] + bv3[jt], 0.0f);
#pragma unroll
    for (int j = 0; j < 8; ++j) t0[j] = (_Float16)myl[m16 * 68 + q * 8 + j];
#pragma unroll
    for (int j = 0; j < 8; ++j) t1[j] = (_Float16)myl[m16 * 68 + 32 + q * 8 + j];
#pragma unroll
    for (int jt = 0; jt < 4; ++jt) {
      acc[jt] = zero4();
      acc[jt] = MFMA(t0, wc1[jt * 2 + 0], acc[jt]);
      acc[jt] = MFMA(t1, wc1[jt * 2 + 1], acc[jt]);
    }
#pragma unroll
    for (int jt = 0; jt < 4; ++jt)
#pragma unroll
      for (int r = 0; r < 4; ++r)
        myl[(q * 4 + r) * 68 + jt * 16 + m16] = fmaxf(acc[jt][r] + bv1[jt], 0.0f);
#pragma unroll
    for (int j = 0; j < 8; ++j) t0[j] = (_Float16)myl[m16 * 68 + q * 8 + j];
#pragma unroll
    for (int j = 0; j < 8; ++j) t1[j] = (_Float16)myl[m16 * 68 + 32 + q * 8 + j];
    f4 o[2];
#pragma unroll
    for (int jt = 0; jt < 2; ++jt) {
      o[jt] = zero4();
      o[jt] = MFMA(t0, wc2[jt * 2 + 0], o[jt]);
      o[jt] = MFMA(t1, wc2[jt * 2 + 1], o[jt]);
    }
#pragma unroll
    for (int jt = 0; jt < 2; ++jt)
#pragma unroll
      for (int r = 0; r < 4; ++r)
        out[(size_t)(rbase + q * 4 + r) * 32 + jt * 16 + m16] =
            __float2half(o[jt][r] + bvo[jt]);
  }
}

// ---- per-graph mean readout; fp16 input ----
__global__ void __launch_bounds__(256) readout_k(const __half* __restrict__ xc,
    const int* __restrict__ batch, int n, float* __restrict__ out) {
  __shared__ float part[8][32];
  int g = blockIdx.x;
  int lo = lbound(batch, n, g);
  int hi = lbound(batch, n, g + 1);
  int j = threadIdx.x & 31, r = threadIdx.x >> 5;
  float acc = 0.0f;
  for (int i = lo + r; i < hi; i += 8) acc += __half2float(xc[(size_t)i * 32 + j]);
  part[r][j] = acc;
  __syncthreads();
  if (threadIdx.x < 32) {
    float s = 0.0f;
#pragma unroll
    for (int rr = 0; rr < 8; ++rr) s += part[rr][j];
    out[g * 32 + j] = (hi > lo) ? s / (float)(hi - lo) : 0.0f;
  }
}

extern "C" void kernel_launch(void* const* d_in, const int* in_sizes, int n_in,
                              void* d_out, int out_size, void* d_ws, size_t ws_size,
                              hipStream_t stream) {
  const float* X    = (const float*)d_in[0];
  const int*   src  = (const int*)d_in[1];
  const int*   dst  = (const int*)d_in[2];
  const int*   batch= (const int*)d_in[3];
  const float* W_in = (const float*)d_in[4];
  const float* b_in = (const float*)d_in[5];
  const float* W1a  = (const float*)d_in[6];
  const float* b1a  = (const float*)d_in[7];
  const float* W1b  = (const float*)d_in[8];
  const float* b1b  = (const float*)d_in[9];
  const float* W2   = (const float*)d_in[10];
  const float* b2   = (const float*)d_in[11];
  const float* W3   = (const float*)d_in[12];
  const float* b3   = (const float*)d_in[13];
  const float* Wc1  = (const float*)d_in[14];
  const float* bc1  = (const float*)d_in[15];
  const float* Wc2  = (const float*)d_in[16];
  const float* bc2  = (const float*)d_in[17];
  float* out = (float*)d_out;

  // workspace layout (~57 MB)
  float* p  = (float*)d_ws;
  __half* xA = (__half*)p; p += (size_t)NN * 32;  // x0 / layer-1 x
  __half* xB = (__half*)p; p += (size_t)NN * 32;  // layer-1 out / layer-2 x
  __half* hz = (__half*)p; p += (size_t)NN * 32;  // h then z (aliased)
  __half* Xe = (__half*)p; p += (size_t)NE * 32;  // Xe; logits at end
  float* invE = p; p += NE;
  _Float16* wbuf = (_Float16*)p; p += WBUF_HALVES / 2 + 16;
  int* q     = (int*)p;
  int* off   = q; q += NE + 1;
  int* bcnt  = q; q += 256;
  int* roff  = q; q += NN + 1;
  int* csr   = q; q += NZ;        // 5.12 MB
  unsigned int* words = (unsigned int*)q; q += CB * CAP;  // 6.4 MB
  __half* h = hz;
  __half* z = hz;            // alias: h fully consumed before z written
  __half* outc = Xe;         // alias: Xe dead after layer-2 zgather

  // CSR-by-dst build + row offsets + weight prep
  prep_misc_k<<<NBLK_ROW + 68, 256, 0, stream>>>(src, roff, bcnt, NN, NZ,
      W_in, W1a, W1b, W2, W3, Wc1, Wc2, wbuf);
  binA_k<<<NBLK_A, 256, 0, stream>>>(src, dst, bcnt, words);

  // binB || layer-1 front half (x=x0=xA, h) in one dispatch
  binB_indual_k<<<CB + MMGRID, 256, 0, stream>>>(words, bcnt, off, invE, csr,
      X, wbuf, b_in, b1a, b1b, xA, h);

  ve_pull_k<<<(NE * 8 + 255) / 256, 256, 0, stream>>>(h, csr, off, invE, Xe, NE);
  zgather_k<<<(NN * 8 + 255) / 256, 256, 0, stream>>>(Xe, dst, roff, z, NN);

  // layer-1 back half + layer-2 front half
  fused_cat_dual<<<MMGRID, 256, 0, stream>>>(xA, z, xA, roff, wbuf, b2, b3, b1a, b1b,
                                             xB, h, NTILE);
  ve_pull_k<<<(NE * 8 + 255) / 256, 256, 0, stream>>>(h, csr, off, invE, Xe, NE);
  zgather_k<<<(NN * 8 + 255) / 256, 256, 0, stream>>>(Xe, dst, roff, z, NN);

  // layer-2 back half + classifier: logits straight to outc
  fused_cat_cls<<<MMGRID, 256, 0, stream>>>(xB, z, xA, roff, wbuf, b2, b3, bc1, bc2,
                                            outc, NTILE);
  readout_k<<<NG, 256, 0, stream>>>(outc, batch, NN, out);
}